// Round 3
// baseline (533.451 us; speedup 1.0000x reference)
//
#include <hip/hip_runtime.h>
#include <hip/hip_bf16.h>

#define BB 8
#define NN 4096
#define HH 12
#define CC 768
#define C3 2304

typedef float  f32x4  __attribute__((ext_vector_type(4)));
typedef __bf16 bf16x8 __attribute__((ext_vector_type(8)));
typedef __bf16 bf16x4 __attribute__((ext_vector_type(4)));

__device__ __forceinline__ void gload16(const void* g, void* l) {
  __builtin_amdgcn_global_load_lds((const __attribute__((address_space(1))) void*)g,
                                   (__attribute__((address_space(3))) void*)l, 16, 0, 0);
}

// ---------------------------------------------------------------------------
// Kernel 1: per (b,h,slice of 256 tokens):
//   Spart[s,bh,i,j] = sum_n q[n,i] * k[n,j]/||k[n]||   (bf16 MFMA, fp32 acc)
//   Qpart[s,bh,i]   = sum_n q[n,i]^2                   (fp32)
// V is NOT touched here anymore (k4 reads it straight from x).
// Double-buffered qT/kT -> ONE barrier per 32-token step.
// ---------------------------------------------------------------------------
__global__ __launch_bounds__(256) void k1_logits(const float* __restrict__ x,
                                                 float* __restrict__ Spart,
                                                 float* __restrict__ Qpart) {
  const int slice = blockIdx.x;        // 0..15 (256 tokens each)
  const int h = blockIdx.y, b = blockIdx.z;
  const int tid = threadIdx.x;
  __shared__ __bf16 qT[2][64][40];     // [buf][chan][token], +8 pad (16B-align)
  __shared__ __bf16 kT[2][64][40];
  __shared__ float  qws[4][64];

  const int t   = tid >> 3;            // token-in-step 0..31
  const int sub = tid & 7;             // chan-group (8 chans)
  const int w   = tid >> 6, lane = tid & 63;
  const int fr  = lane & 15, fk = lane >> 4;
  const int c0  = sub * 8;

  const float* qbase = x + (size_t)(b * NN + slice * 256) * C3 + h * 64 + c0;

  float qss8[8];
#pragma unroll
  for (int j = 0; j < 8; ++j) qss8[j] = 0.f;
  f32x4 acc[4];
#pragma unroll
  for (int tn = 0; tn < 4; ++tn) acc[tn] = (f32x4){0.f, 0.f, 0.f, 0.f};

  // --- prologue: stage step 0 into buffer 0
  {
    const float* qp = qbase + (size_t)t * C3;
    const float4 q0 = *(const float4*)(qp);
    const float4 q1 = *(const float4*)(qp + 4);
    const float4 k0 = *(const float4*)(qp + 768);
    const float4 k1 = *(const float4*)(qp + 772);
    float ss = k0.x * k0.x + k0.y * k0.y + k0.z * k0.z + k0.w * k0.w +
               k1.x * k1.x + k1.y * k1.y + k1.z * k1.z + k1.w * k1.w;
    ss += __shfl_xor(ss, 1);
    ss += __shfl_xor(ss, 2);
    ss += __shfl_xor(ss, 4);
    const float inv = 1.0f / fmaxf(sqrtf(ss), 1e-12f);
    qT[0][c0 + 0][t] = (__bf16)q0.x; qT[0][c0 + 1][t] = (__bf16)q0.y;
    qT[0][c0 + 2][t] = (__bf16)q0.z; qT[0][c0 + 3][t] = (__bf16)q0.w;
    qT[0][c0 + 4][t] = (__bf16)q1.x; qT[0][c0 + 5][t] = (__bf16)q1.y;
    qT[0][c0 + 6][t] = (__bf16)q1.z; qT[0][c0 + 7][t] = (__bf16)q1.w;
    kT[0][c0 + 0][t] = (__bf16)(k0.x * inv); kT[0][c0 + 1][t] = (__bf16)(k0.y * inv);
    kT[0][c0 + 2][t] = (__bf16)(k0.z * inv); kT[0][c0 + 3][t] = (__bf16)(k0.w * inv);
    kT[0][c0 + 4][t] = (__bf16)(k1.x * inv); kT[0][c0 + 5][t] = (__bf16)(k1.y * inv);
    kT[0][c0 + 6][t] = (__bf16)(k1.z * inv); kT[0][c0 + 7][t] = (__bf16)(k1.w * inv);
    qss8[0] = fmaf(q0.x, q0.x, qss8[0]); qss8[1] = fmaf(q0.y, q0.y, qss8[1]);
    qss8[2] = fmaf(q0.z, q0.z, qss8[2]); qss8[3] = fmaf(q0.w, q0.w, qss8[3]);
    qss8[4] = fmaf(q1.x, q1.x, qss8[4]); qss8[5] = fmaf(q1.y, q1.y, qss8[5]);
    qss8[6] = fmaf(q1.z, q1.z, qss8[6]); qss8[7] = fmaf(q1.w, q1.w, qss8[7]);
  }
  __syncthreads();

#pragma unroll
  for (int step = 0; step < 8; ++step) {
    const int cur = step & 1;
    // issue next-step global loads early (hide latency under MFMA)
    float4 q0, q1, k0, k1;
    if (step < 7) {
      const float* np = qbase + (size_t)((step + 1) * 32 + t) * C3;
      q0 = *(const float4*)(np);
      q1 = *(const float4*)(np + 4);
      k0 = *(const float4*)(np + 768);
      k1 = *(const float4*)(np + 772);
    }
    const bf16x8 afr = *(const bf16x8*)&qT[cur][w * 16 + fr][fk * 8];
    const bf16x8 b0 = *(const bf16x8*)&kT[cur][0 * 16 + fr][fk * 8];
    const bf16x8 b1 = *(const bf16x8*)&kT[cur][1 * 16 + fr][fk * 8];
    const bf16x8 b2 = *(const bf16x8*)&kT[cur][2 * 16 + fr][fk * 8];
    const bf16x8 b3 = *(const bf16x8*)&kT[cur][3 * 16 + fr][fk * 8];
    acc[0] = __builtin_amdgcn_mfma_f32_16x16x32_bf16(afr, b0, acc[0], 0, 0, 0);
    acc[1] = __builtin_amdgcn_mfma_f32_16x16x32_bf16(afr, b1, acc[1], 0, 0, 0);
    acc[2] = __builtin_amdgcn_mfma_f32_16x16x32_bf16(afr, b2, acc[2], 0, 0, 0);
    acc[3] = __builtin_amdgcn_mfma_f32_16x16x32_bf16(afr, b3, acc[3], 0, 0, 0);
    if (step < 7) {
      const int nxt = cur ^ 1;
      float ss = k0.x * k0.x + k0.y * k0.y + k0.z * k0.z + k0.w * k0.w +
                 k1.x * k1.x + k1.y * k1.y + k1.z * k1.z + k1.w * k1.w;
      ss += __shfl_xor(ss, 1);
      ss += __shfl_xor(ss, 2);
      ss += __shfl_xor(ss, 4);
      const float inv = 1.0f / fmaxf(sqrtf(ss), 1e-12f);
      qT[nxt][c0 + 0][t] = (__bf16)q0.x; qT[nxt][c0 + 1][t] = (__bf16)q0.y;
      qT[nxt][c0 + 2][t] = (__bf16)q0.z; qT[nxt][c0 + 3][t] = (__bf16)q0.w;
      qT[nxt][c0 + 4][t] = (__bf16)q1.x; qT[nxt][c0 + 5][t] = (__bf16)q1.y;
      qT[nxt][c0 + 6][t] = (__bf16)q1.z; qT[nxt][c0 + 7][t] = (__bf16)q1.w;
      kT[nxt][c0 + 0][t] = (__bf16)(k0.x * inv); kT[nxt][c0 + 1][t] = (__bf16)(k0.y * inv);
      kT[nxt][c0 + 2][t] = (__bf16)(k0.z * inv); kT[nxt][c0 + 3][t] = (__bf16)(k0.w * inv);
      kT[nxt][c0 + 4][t] = (__bf16)(k1.x * inv); kT[nxt][c0 + 5][t] = (__bf16)(k1.y * inv);
      kT[nxt][c0 + 6][t] = (__bf16)(k1.z * inv); kT[nxt][c0 + 7][t] = (__bf16)(k1.w * inv);
      qss8[0] = fmaf(q0.x, q0.x, qss8[0]); qss8[1] = fmaf(q0.y, q0.y, qss8[1]);
      qss8[2] = fmaf(q0.z, q0.z, qss8[2]); qss8[3] = fmaf(q0.w, q0.w, qss8[3]);
      qss8[4] = fmaf(q1.x, q1.x, qss8[4]); qss8[5] = fmaf(q1.y, q1.y, qss8[5]);
      qss8[6] = fmaf(q1.z, q1.z, qss8[6]); qss8[7] = fmaf(q1.w, q1.w, qss8[7]);
    }
    __syncthreads();
  }

  // S partial store: C/D layout col=lane&15, row=(lane>>4)*4+reg
  const int bh = b * HH + h;
  float* Sp = Spart + ((size_t)(slice * 96 + bh)) * 4096;
#pragma unroll
  for (int tn = 0; tn < 4; ++tn)
#pragma unroll
    for (int rr = 0; rr < 4; ++rr)
      Sp[(w * 16 + fk * 4 + rr) * 64 + tn * 16 + fr] = acc[tn][rr];

  // qss: reduce over the wave's 8 tokens (lane bits 3..5), then across waves
#pragma unroll
  for (int j = 0; j < 8; ++j) {
    float v = qss8[j];
    v += __shfl_xor(v, 8);
    v += __shfl_xor(v, 16);
    v += __shfl_xor(v, 32);
    if (lane < 8) qws[w][lane * 8 + j] = v;
  }
  __syncthreads();
  if (tid < 64) {
    const float qs = qws[0][tid] + qws[1][tid] + qws[2][tid] + qws[3][tid];
    Qpart[((size_t)(slice * 96 + bh)) * 64 + tid] = qs;
  }
}

// ---------------------------------------------------------------------------
// Kernel 2: sum 16 slice-partials, then row softmax with q-norm + temperature
// 512 thr/block, 8 lanes per row (8 cols each), grid (12,8)
// ---------------------------------------------------------------------------
__global__ __launch_bounds__(512) void k2_softmax(const float* __restrict__ Spart,
                                                  const float* __restrict__ Qpart,
                                                  const float* __restrict__ temp,
                                                  float* __restrict__ attn) {
  const int h = blockIdx.x, b = blockIdx.y;
  const int tid = threadIdx.x;
  const int i = tid >> 3;       // row 0..63
  const int g = tid & 7;        // eighth of the row (8 cols)
  const int bh = b * HH + h;
  float qs = 0.f;
#pragma unroll
  for (int s = 0; s < 16; ++s) qs += Qpart[((size_t)(s * 96 + bh)) * 64 + i];
  float v[8];
#pragma unroll
  for (int j = 0; j < 8; ++j) v[j] = 0.f;
#pragma unroll 4
  for (int s = 0; s < 16; ++s) {
    const float* Sp = Spart + ((size_t)(s * 96 + bh)) * 4096 + i * 64 + g * 8;
    const float4 t0 = *(const float4*)(Sp);
    const float4 t1 = *(const float4*)(Sp + 4);
    v[0] += t0.x; v[1] += t0.y; v[2] += t0.z; v[3] += t0.w;
    v[4] += t1.x; v[5] += t1.y; v[6] += t1.z; v[7] += t1.w;
  }
  const float rqs = 1.0f / fmaxf(sqrtf(qs), 1e-12f);
  const float tp  = temp[h] * rqs;
  float m = -3.4e38f;
#pragma unroll
  for (int j = 0; j < 8; ++j) { v[j] *= tp; m = fmaxf(m, v[j]); }
  m = fmaxf(m, __shfl_xor(m, 1));
  m = fmaxf(m, __shfl_xor(m, 2));
  m = fmaxf(m, __shfl_xor(m, 4));
  float s = 0.f;
#pragma unroll
  for (int j = 0; j < 8; ++j) { v[j] = __expf(v[j] - m); s += v[j]; }
  s += __shfl_xor(s, 1);
  s += __shfl_xor(s, 2);
  s += __shfl_xor(s, 4);
  const float inv = 1.0f / s;
  float* Ap = attn + (size_t)bh * 4096 + i * 64 + g * 8;
  float4 o0, o1;
  o0.x = v[0] * inv; o0.y = v[1] * inv; o0.z = v[2] * inv; o0.w = v[3] * inv;
  o1.x = v[4] * inv; o1.y = v[5] * inv; o1.z = v[6] * inv; o1.w = v[7] * inv;
  *(float4*)(Ap)     = o0;
  *(float4*)(Ap + 4) = o1;
}

// ---------------------------------------------------------------------------
// Kernel 3: W2[b,co,h*64+j] = sum_i proj_w[co,h*64+i] * attn[b,h,i,j]  (bf16)
// ---------------------------------------------------------------------------
__global__ __launch_bounds__(256) void k3_w2(const float* __restrict__ attn,
                                             const float* __restrict__ pw,
                                             __bf16* __restrict__ W2) {
  const int ct = blockIdx.x, h = blockIdx.y, b = blockIdx.z;
  const int co0 = ct * 64;
  __shared__ float pT[64][65];
  __shared__ float ab[64][64];
  const int tid = threadIdx.x;
  const int r = tid >> 2, c0 = (tid & 3) * 16;
  {
    const float* pp = pw + (size_t)(co0 + r) * CC + h * 64 + c0;
    const float4 p0 = *(const float4*)(pp + 0);
    const float4 p1 = *(const float4*)(pp + 4);
    const float4 p2 = *(const float4*)(pp + 8);
    const float4 p3 = *(const float4*)(pp + 12);
    const float* ap = attn + (size_t)(b * HH + h) * 4096 + r * 64 + c0;
    const float4 a0 = *(const float4*)(ap + 0);
    const float4 a1 = *(const float4*)(ap + 4);
    const float4 a2 = *(const float4*)(ap + 8);
    const float4 a3 = *(const float4*)(ap + 12);
    pT[c0 +  0][r] = p0.x; pT[c0 +  1][r] = p0.y; pT[c0 +  2][r] = p0.z; pT[c0 +  3][r] = p0.w;
    pT[c0 +  4][r] = p1.x; pT[c0 +  5][r] = p1.y; pT[c0 +  6][r] = p1.z; pT[c0 +  7][r] = p1.w;
    pT[c0 +  8][r] = p2.x; pT[c0 +  9][r] = p2.y; pT[c0 + 10][r] = p2.z; pT[c0 + 11][r] = p2.w;
    pT[c0 + 12][r] = p3.x; pT[c0 + 13][r] = p3.y; pT[c0 + 14][r] = p3.z; pT[c0 + 15][r] = p3.w;
    *(float4*)&ab[r][c0 + 0]  = a0;
    *(float4*)&ab[r][c0 + 4]  = a1;
    *(float4*)&ab[r][c0 + 8]  = a2;
    *(float4*)&ab[r][c0 + 12] = a3;
  }
  __syncthreads();
  const int col = tid & 63, jg = tid >> 6;
  float accJ[16];
#pragma unroll
  for (int c = 0; c < 16; ++c) accJ[c] = 0.f;
#pragma unroll 4
  for (int i = 0; i < 64; ++i) {
    const float p = pT[i][col];
    const float4* a4 = (const float4*)&ab[i][jg * 16];
    const float4 A0 = a4[0], A1 = a4[1], A2 = a4[2], A3 = a4[3];
    accJ[0]  = fmaf(p, A0.x, accJ[0]);  accJ[1]  = fmaf(p, A0.y, accJ[1]);
    accJ[2]  = fmaf(p, A0.z, accJ[2]);  accJ[3]  = fmaf(p, A0.w, accJ[3]);
    accJ[4]  = fmaf(p, A1.x, accJ[4]);  accJ[5]  = fmaf(p, A1.y, accJ[5]);
    accJ[6]  = fmaf(p, A1.z, accJ[6]);  accJ[7]  = fmaf(p, A1.w, accJ[7]);
    accJ[8]  = fmaf(p, A2.x, accJ[8]);  accJ[9]  = fmaf(p, A2.y, accJ[9]);
    accJ[10] = fmaf(p, A2.z, accJ[10]); accJ[11] = fmaf(p, A2.w, accJ[11]);
    accJ[12] = fmaf(p, A3.x, accJ[12]); accJ[13] = fmaf(p, A3.y, accJ[13]);
    accJ[14] = fmaf(p, A3.z, accJ[14]); accJ[15] = fmaf(p, A3.w, accJ[15]);
  }
  bf16x8 u0, u1;
#pragma unroll
  for (int c = 0; c < 8; ++c) { u0[c] = (__bf16)accJ[c]; u1[c] = (__bf16)accJ[8 + c]; }
  __bf16* wp = W2 + ((size_t)b * CC + co0 + col) * CC + h * 64 + jg * 16;
  *(bf16x8*)(wp)     = u0;
  *(bf16x8*)(wp + 8) = u1;
}

// ---------------------------------------------------------------------------
// Kernel 4: per-batch GEMM  out[b,n,co] = sum_c' V[b,n,c'] * W2[b,co,c'] + pb[co]
// A (=V) is staged straight from fp32 x with on-the-fly bf16 convert
// (reg-staged, next-step loads issued before MFMA). B uses global_load_lds.
// Bijective XCD swizzle: 1536 blocks, 192/XCD = exactly one batch per XCD.
// ---------------------------------------------------------------------------
__global__ __launch_bounds__(256) void k4_gemm(const float* __restrict__ x,
                                               const __bf16* __restrict__ W2,
                                               const float* __restrict__ pb,
                                               float* __restrict__ out) {
  // XCD swizzle: nwg=1536, nwg%8==0 -> wgid=(id%8)*192+id/8
  const int id0 = blockIdx.x;
  const int id = (id0 & 7) * 192 + (id0 >> 3);
  const int bz = id / 192;
  const int rem = id - bz * 192;
  const int mg = rem / 48;
  const int idx = rem - mg * 48;
  const int nt = idx >> 3;
  const int mt = mg * 8 + (idx & 7);
  const int m0 = mt * 128, co0 = nt * 128;

  __shared__ __bf16 At[128][32];
  __shared__ __bf16 Bt[128][32];

  const int tid  = threadIdx.x;
  const int w    = tid >> 6, lane = tid & 63;
  const int wm   = w >> 1,   wn   = w & 1;
  const int fr   = lane & 15;
  const int fk   = lane >> 4;

  f32x4 acc[4][4];
#pragma unroll
  for (int tm = 0; tm < 4; ++tm)
#pragma unroll
    for (int tn = 0; tn < 4; ++tn) acc[tm][tn] = (f32x4){0.f, 0.f, 0.f, 0.f};

  // B staging (bf16, async direct-to-LDS)
  const int srow = lane >> 2;
  const int scol = (lane & 3) * 8;
  const __bf16* Bg = W2 + ((size_t)bz * CC + co0 + w * 32 + srow) * CC + scol;
  __bf16* lB0 = &Bt[w * 32][0];
  __bf16* lB1 = &Bt[w * 32 + 16][0];

  // A staging from x V-third (fp32 -> bf16): row=tid>>1, half=(tid&1)*16
  const int arow = tid >> 1;
  const int ah   = (tid & 1) * 16;
  const float* Ax = x + (size_t)(bz * NN + m0 + arow) * C3 + 1536 + ah;

  // prologue: A regs for kk=0
  float4 a0 = *(const float4*)(Ax + 0);
  float4 a1 = *(const float4*)(Ax + 4);
  float4 a2 = *(const float4*)(Ax + 8);
  float4 a3 = *(const float4*)(Ax + 12);

  for (int kk = 0; kk < 24; ++kk) {
    const int kb = kk * 32;
    __syncthreads();
    gload16(Bg + kb,            lB0);
    gload16(Bg + 16 * CC + kb,  lB1);
    bf16x8 u0, u1;
    u0[0] = (__bf16)a0.x; u0[1] = (__bf16)a0.y; u0[2] = (__bf16)a0.z; u0[3] = (__bf16)a0.w;
    u0[4] = (__bf16)a1.x; u0[5] = (__bf16)a1.y; u0[6] = (__bf16)a1.z; u0[7] = (__bf16)a1.w;
    u1[0] = (__bf16)a2.x; u1[1] = (__bf16)a2.y; u1[2] = (__bf16)a2.z; u1[3] = (__bf16)a2.w;
    u1[4] = (__bf16)a3.x; u1[5] = (__bf16)a3.y; u1[6] = (__bf16)a3.z; u1[7] = (__bf16)a3.w;
    *(bf16x8*)&At[arow][ah]     = u0;
    *(bf16x8*)&At[arow][ah + 8] = u1;
    if (kk < 23) {
      const float* nx = Ax + kb + 32;
      a0 = *(const float4*)(nx + 0);
      a1 = *(const float4*)(nx + 4);
      a2 = *(const float4*)(nx + 8);
      a3 = *(const float4*)(nx + 12);
    }
    __syncthreads();
    bf16x8 afr[4], bfr[4];
#pragma unroll
    for (int tm = 0; tm < 4; ++tm)
      afr[tm] = *(const bf16x8*)&At[wm * 64 + tm * 16 + fr][fk * 8];
#pragma unroll
    for (int tn = 0; tn < 4; ++tn)
      bfr[tn] = *(const bf16x8*)&Bt[wn * 64 + tn * 16 + fr][fk * 8];
#pragma unroll
    for (int tm = 0; tm < 4; ++tm)
#pragma unroll
      for (int tn = 0; tn < 4; ++tn)
        acc[tm][tn] = __builtin_amdgcn_mfma_f32_16x16x32_bf16(afr[tm], bfr[tn],
                                                              acc[tm][tn], 0, 0, 0);
  }

#pragma unroll
  for (int tn = 0; tn < 4; ++tn) {
    const int co = co0 + wn * 64 + tn * 16 + fr;
    const float bias = pb[co];
#pragma unroll
    for (int tm = 0; tm < 4; ++tm) {
#pragma unroll
      for (int rr = 0; rr < 4; ++rr) {
        const int row = m0 + wm * 64 + tm * 16 + fk * 4 + rr;
        out[(size_t)(bz * NN + row) * CC + co] = acc[tm][tn][rr] + bias;
      }
    }
  }
}

// ---------------------------------------------------------------------------
extern "C" void kernel_launch(void* const* d_in, const int* in_sizes, int n_in,
                              void* d_out, int out_size, void* d_ws, size_t ws_size,
                              hipStream_t stream) {
  const float* x    = (const float*)d_in[0];
  const float* temp = (const float*)d_in[1];
  const float* pw   = (const float*)d_in[2];
  const float* pb   = (const float*)d_in[3];
  float* out = (float*)d_out;
  char* ws = (char*)d_ws;

  // ws layout (bytes) — every buffer fully overwritten each call, no memset:
  //   Spart @ 0        : 16*96*4096*4 = 25,165,824
  //   Qpart @ 25165824 : 16*96*64*4   = 393,216
  //   attn  @ 25559040 : 1,572,864
  //   W2    @ 27131904 : 9,437,184    (total ~37 MB)
  float*  Spart = (float*)(ws);
  float*  Qpart = (float*)(ws + 25165824);
  float*  attn  = (float*)(ws + 25559040);
  __bf16* W2    = (__bf16*)(ws + 27131904);

  hipLaunchKernelGGL(k1_logits,  dim3(16, 12, 8), dim3(256), 0, stream, x, Spart, Qpart);
  hipLaunchKernelGGL(k2_softmax, dim3(12, 8),     dim3(512), 0, stream, Spart, Qpart, temp, attn);
  hipLaunchKernelGGL(k3_w2,      dim3(12, 12, 8), dim3(256), 0, stream, attn, pw, W2);
  hipLaunchKernelGGL(k4_gemm,    dim3(1536),      dim3(256), 0, stream, x, W2, pb, out);
}

// Round 4
// 524.347 us; speedup vs baseline: 1.0174x; 1.0174x over previous
//
#include <hip/hip_runtime.h>
#include <hip/hip_bf16.h>

#define BB 8
#define NN 4096
#define HH 12
#define CC 768
#define C3 2304

typedef float  f32x4  __attribute__((ext_vector_type(4)));
typedef __bf16 bf16x8 __attribute__((ext_vector_type(8)));
typedef __bf16 bf16x4 __attribute__((ext_vector_type(4)));

__device__ __forceinline__ void gload16(const void* g, void* l) {
  __builtin_amdgcn_global_load_lds((const __attribute__((address_space(1))) void*)g,
                                   (__attribute__((address_space(3))) void*)l, 16, 0, 0);
}

// ---------------------------------------------------------------------------
// Kernel 1: per (b,h,slice of 256 tokens):
//   Spart[s,bh,i,j] = sum_n q[n,i] * k[n,j]/||k[n]||   (bf16 MFMA, fp32 acc)
//   Qpart[s,bh,i]   = sum_n q[n,i]^2                   (fp32)
//   vb[b*N+n][h*64+c] = (bf16) x[b,n,1536+h*64+c]      (V convert, post-loop)
// Double-buffered qT/kT -> ONE barrier per 32-token step. V pass runs after
// the loop with zero barriers so its stores never hit a vmcnt(0) drain.
// ---------------------------------------------------------------------------
__global__ __launch_bounds__(256) void k1_logits(const float* __restrict__ x,
                                                 __bf16* __restrict__ vb,
                                                 float* __restrict__ Spart,
                                                 float* __restrict__ Qpart) {
  const int slice = blockIdx.x;        // 0..15 (256 tokens each)
  const int h = blockIdx.y, b = blockIdx.z;
  const int tid = threadIdx.x;
  __shared__ __bf16 qT[2][64][40];     // [buf][chan][token], +8 pad (16B-align)
  __shared__ __bf16 kT[2][64][40];
  __shared__ float  qws[4][64];

  const int t   = tid >> 3;            // token-in-step 0..31
  const int sub = tid & 7;             // chan-group (8 chans)
  const int w   = tid >> 6, lane = tid & 63;
  const int fr  = lane & 15, fk = lane >> 4;
  const int c0  = sub * 8;

  const float* qbase = x + (size_t)(b * NN + slice * 256) * C3 + h * 64 + c0;

  float qss8[8];
#pragma unroll
  for (int j = 0; j < 8; ++j) qss8[j] = 0.f;
  f32x4 acc[4];
#pragma unroll
  for (int tn = 0; tn < 4; ++tn) acc[tn] = (f32x4){0.f, 0.f, 0.f, 0.f};

  // --- prologue: stage step 0 into buffer 0
  {
    const float* qp = qbase + (size_t)t * C3;
    const float4 q0 = *(const float4*)(qp);
    const float4 q1 = *(const float4*)(qp + 4);
    const float4 k0 = *(const float4*)(qp + 768);
    const float4 k1 = *(const float4*)(qp + 772);
    float ss = k0.x * k0.x + k0.y * k0.y + k0.z * k0.z + k0.w * k0.w +
               k1.x * k1.x + k1.y * k1.y + k1.z * k1.z + k1.w * k1.w;
    ss += __shfl_xor(ss, 1);
    ss += __shfl_xor(ss, 2);
    ss += __shfl_xor(ss, 4);
    const float inv = 1.0f / fmaxf(sqrtf(ss), 1e-12f);
    qT[0][c0 + 0][t] = (__bf16)q0.x; qT[0][c0 + 1][t] = (__bf16)q0.y;
    qT[0][c0 + 2][t] = (__bf16)q0.z; qT[0][c0 + 3][t] = (__bf16)q0.w;
    qT[0][c0 + 4][t] = (__bf16)q1.x; qT[0][c0 + 5][t] = (__bf16)q1.y;
    qT[0][c0 + 6][t] = (__bf16)q1.z; qT[0][c0 + 7][t] = (__bf16)q1.w;
    kT[0][c0 + 0][t] = (__bf16)(k0.x * inv); kT[0][c0 + 1][t] = (__bf16)(k0.y * inv);
    kT[0][c0 + 2][t] = (__bf16)(k0.z * inv); kT[0][c0 + 3][t] = (__bf16)(k0.w * inv);
    kT[0][c0 + 4][t] = (__bf16)(k1.x * inv); kT[0][c0 + 5][t] = (__bf16)(k1.y * inv);
    kT[0][c0 + 6][t] = (__bf16)(k1.z * inv); kT[0][c0 + 7][t] = (__bf16)(k1.w * inv);
    qss8[0] = fmaf(q0.x, q0.x, qss8[0]); qss8[1] = fmaf(q0.y, q0.y, qss8[1]);
    qss8[2] = fmaf(q0.z, q0.z, qss8[2]); qss8[3] = fmaf(q0.w, q0.w, qss8[3]);
    qss8[4] = fmaf(q1.x, q1.x, qss8[4]); qss8[5] = fmaf(q1.y, q1.y, qss8[5]);
    qss8[6] = fmaf(q1.z, q1.z, qss8[6]); qss8[7] = fmaf(q1.w, q1.w, qss8[7]);
  }
  __syncthreads();

#pragma unroll
  for (int step = 0; step < 8; ++step) {
    const int cur = step & 1;
    // issue next-step global loads early (hide latency under MFMA)
    float4 q0, q1, k0, k1;
    if (step < 7) {
      const float* np = qbase + (size_t)((step + 1) * 32 + t) * C3;
      q0 = *(const float4*)(np);
      q1 = *(const float4*)(np + 4);
      k0 = *(const float4*)(np + 768);
      k1 = *(const float4*)(np + 772);
    }
    const bf16x8 afr = *(const bf16x8*)&qT[cur][w * 16 + fr][fk * 8];
    const bf16x8 b0 = *(const bf16x8*)&kT[cur][0 * 16 + fr][fk * 8];
    const bf16x8 b1 = *(const bf16x8*)&kT[cur][1 * 16 + fr][fk * 8];
    const bf16x8 b2 = *(const bf16x8*)&kT[cur][2 * 16 + fr][fk * 8];
    const bf16x8 b3 = *(const bf16x8*)&kT[cur][3 * 16 + fr][fk * 8];
    acc[0] = __builtin_amdgcn_mfma_f32_16x16x32_bf16(afr, b0, acc[0], 0, 0, 0);
    acc[1] = __builtin_amdgcn_mfma_f32_16x16x32_bf16(afr, b1, acc[1], 0, 0, 0);
    acc[2] = __builtin_amdgcn_mfma_f32_16x16x32_bf16(afr, b2, acc[2], 0, 0, 0);
    acc[3] = __builtin_amdgcn_mfma_f32_16x16x32_bf16(afr, b3, acc[3], 0, 0, 0);
    if (step < 7) {
      const int nxt = cur ^ 1;
      float ss = k0.x * k0.x + k0.y * k0.y + k0.z * k0.z + k0.w * k0.w +
                 k1.x * k1.x + k1.y * k1.y + k1.z * k1.z + k1.w * k1.w;
      ss += __shfl_xor(ss, 1);
      ss += __shfl_xor(ss, 2);
      ss += __shfl_xor(ss, 4);
      const float inv = 1.0f / fmaxf(sqrtf(ss), 1e-12f);
      qT[nxt][c0 + 0][t] = (__bf16)q0.x; qT[nxt][c0 + 1][t] = (__bf16)q0.y;
      qT[nxt][c0 + 2][t] = (__bf16)q0.z; qT[nxt][c0 + 3][t] = (__bf16)q0.w;
      qT[nxt][c0 + 4][t] = (__bf16)q1.x; qT[nxt][c0 + 5][t] = (__bf16)q1.y;
      qT[nxt][c0 + 6][t] = (__bf16)q1.z; qT[nxt][c0 + 7][t] = (__bf16)q1.w;
      kT[nxt][c0 + 0][t] = (__bf16)(k0.x * inv); kT[nxt][c0 + 1][t] = (__bf16)(k0.y * inv);
      kT[nxt][c0 + 2][t] = (__bf16)(k0.z * inv); kT[nxt][c0 + 3][t] = (__bf16)(k0.w * inv);
      kT[nxt][c0 + 4][t] = (__bf16)(k1.x * inv); kT[nxt][c0 + 5][t] = (__bf16)(k1.y * inv);
      kT[nxt][c0 + 6][t] = (__bf16)(k1.z * inv); kT[nxt][c0 + 7][t] = (__bf16)(k1.w * inv);
      qss8[0] = fmaf(q0.x, q0.x, qss8[0]); qss8[1] = fmaf(q0.y, q0.y, qss8[1]);
      qss8[2] = fmaf(q0.z, q0.z, qss8[2]); qss8[3] = fmaf(q0.w, q0.w, qss8[3]);
      qss8[4] = fmaf(q1.x, q1.x, qss8[4]); qss8[5] = fmaf(q1.y, q1.y, qss8[5]);
      qss8[6] = fmaf(q1.z, q1.z, qss8[6]); qss8[7] = fmaf(q1.w, q1.w, qss8[7]);
    }
    __syncthreads();
  }

  // S partial store: C/D layout col=lane&15, row=(lane>>4)*4+reg
  const int bh = b * HH + h;
  float* Sp = Spart + ((size_t)(slice * 96 + bh)) * 4096;
#pragma unroll
  for (int tn = 0; tn < 4; ++tn)
#pragma unroll
    for (int rr = 0; rr < 4; ++rr)
      Sp[(w * 16 + fk * 4 + rr) * 64 + tn * 16 + fr] = acc[tn][rr];

  // qss: reduce over the wave's 8 tokens (lane bits 3..5), then across waves
#pragma unroll
  for (int j = 0; j < 8; ++j) {
    float v = qss8[j];
    v += __shfl_xor(v, 8);
    v += __shfl_xor(v, 16);
    v += __shfl_xor(v, 32);
    if (lane < 8) qws[w][lane * 8 + j] = v;
  }
  __syncthreads();
  if (tid < 64) {
    const float qs = qws[0][tid] + qws[1][tid] + qws[2][tid] + qws[3][tid];
    Qpart[((size_t)(slice * 96 + bh)) * 64 + tid] = qs;
  }

  // --- V pass (no barriers, fire-and-forget): 256 tokens x 64 chans
  const float* vsrc = x + (size_t)(b * NN + slice * 256) * C3 + 1536 + h * 64 + c0;
  __bf16* vdst = vb + (size_t)(b * NN + slice * 256) * CC + h * 64 + c0;
#pragma unroll
  for (int r = 0; r < 8; ++r) {
    const size_t tok = (size_t)(r * 32 + t);
    const float4 v0 = *(const float4*)(vsrc + tok * C3);
    const float4 v1 = *(const float4*)(vsrc + tok * C3 + 4);
    bf16x8 vv;
    vv[0] = (__bf16)v0.x; vv[1] = (__bf16)v0.y; vv[2] = (__bf16)v0.z; vv[3] = (__bf16)v0.w;
    vv[4] = (__bf16)v1.x; vv[5] = (__bf16)v1.y; vv[6] = (__bf16)v1.z; vv[7] = (__bf16)v1.w;
    *(bf16x8*)(vdst + tok * CC) = vv;
  }
}

// ---------------------------------------------------------------------------
// Kernel 2: sum 16 slice-partials, then row softmax with q-norm + temperature
// 512 thr/block, 8 lanes per row (8 cols each), grid (12,8)
// ---------------------------------------------------------------------------
__global__ __launch_bounds__(512) void k2_softmax(const float* __restrict__ Spart,
                                                  const float* __restrict__ Qpart,
                                                  const float* __restrict__ temp,
                                                  float* __restrict__ attn) {
  const int h = blockIdx.x, b = blockIdx.y;
  const int tid = threadIdx.x;
  const int i = tid >> 3;       // row 0..63
  const int g = tid & 7;        // eighth of the row (8 cols)
  const int bh = b * HH + h;
  float qs = 0.f;
#pragma unroll
  for (int s = 0; s < 16; ++s) qs += Qpart[((size_t)(s * 96 + bh)) * 64 + i];
  float v[8];
#pragma unroll
  for (int j = 0; j < 8; ++j) v[j] = 0.f;
#pragma unroll 4
  for (int s = 0; s < 16; ++s) {
    const float* Sp = Spart + ((size_t)(s * 96 + bh)) * 4096 + i * 64 + g * 8;
    const float4 t0 = *(const float4*)(Sp);
    const float4 t1 = *(const float4*)(Sp + 4);
    v[0] += t0.x; v[1] += t0.y; v[2] += t0.z; v[3] += t0.w;
    v[4] += t1.x; v[5] += t1.y; v[6] += t1.z; v[7] += t1.w;
  }
  const float rqs = 1.0f / fmaxf(sqrtf(qs), 1e-12f);
  const float tp  = temp[h] * rqs;
  float m = -3.4e38f;
#pragma unroll
  for (int j = 0; j < 8; ++j) { v[j] *= tp; m = fmaxf(m, v[j]); }
  m = fmaxf(m, __shfl_xor(m, 1));
  m = fmaxf(m, __shfl_xor(m, 2));
  m = fmaxf(m, __shfl_xor(m, 4));
  float s = 0.f;
#pragma unroll
  for (int j = 0; j < 8; ++j) { v[j] = __expf(v[j] - m); s += v[j]; }
  s += __shfl_xor(s, 1);
  s += __shfl_xor(s, 2);
  s += __shfl_xor(s, 4);
  const float inv = 1.0f / s;
  float* Ap = attn + (size_t)bh * 4096 + i * 64 + g * 8;
  float4 o0, o1;
  o0.x = v[0] * inv; o0.y = v[1] * inv; o0.z = v[2] * inv; o0.w = v[3] * inv;
  o1.x = v[4] * inv; o1.y = v[5] * inv; o1.z = v[6] * inv; o1.w = v[7] * inv;
  *(float4*)(Ap)     = o0;
  *(float4*)(Ap + 4) = o1;
}

// ---------------------------------------------------------------------------
// Kernel 3: W2[b,co,h*64+j] = sum_i proj_w[co,h*64+i] * attn[b,h,i,j]  (bf16)
// ---------------------------------------------------------------------------
__global__ __launch_bounds__(256) void k3_w2(const float* __restrict__ attn,
                                             const float* __restrict__ pw,
                                             __bf16* __restrict__ W2) {
  const int ct = blockIdx.x, h = blockIdx.y, b = blockIdx.z;
  const int co0 = ct * 64;
  __shared__ float pT[64][65];
  __shared__ float ab[64][64];
  const int tid = threadIdx.x;
  const int r = tid >> 2, c0 = (tid & 3) * 16;
  {
    const float* pp = pw + (size_t)(co0 + r) * CC + h * 64 + c0;
    const float4 p0 = *(const float4*)(pp + 0);
    const float4 p1 = *(const float4*)(pp + 4);
    const float4 p2 = *(const float4*)(pp + 8);
    const float4 p3 = *(const float4*)(pp + 12);
    const float* ap = attn + (size_t)(b * HH + h) * 4096 + r * 64 + c0;
    const float4 a0 = *(const float4*)(ap + 0);
    const float4 a1 = *(const float4*)(ap + 4);
    const float4 a2 = *(const float4*)(ap + 8);
    const float4 a3 = *(const float4*)(ap + 12);
    pT[c0 +  0][r] = p0.x; pT[c0 +  1][r] = p0.y; pT[c0 +  2][r] = p0.z; pT[c0 +  3][r] = p0.w;
    pT[c0 +  4][r] = p1.x; pT[c0 +  5][r] = p1.y; pT[c0 +  6][r] = p1.z; pT[c0 +  7][r] = p1.w;
    pT[c0 +  8][r] = p2.x; pT[c0 +  9][r] = p2.y; pT[c0 + 10][r] = p2.z; pT[c0 + 11][r] = p2.w;
    pT[c0 + 12][r] = p3.x; pT[c0 + 13][r] = p3.y; pT[c0 + 14][r] = p3.z; pT[c0 + 15][r] = p3.w;
    *(float4*)&ab[r][c0 + 0]  = a0;
    *(float4*)&ab[r][c0 + 4]  = a1;
    *(float4*)&ab[r][c0 + 8]  = a2;
    *(float4*)&ab[r][c0 + 12] = a3;
  }
  __syncthreads();
  const int col = tid & 63, jg = tid >> 6;
  float accJ[16];
#pragma unroll
  for (int c = 0; c < 16; ++c) accJ[c] = 0.f;
#pragma unroll 4
  for (int i = 0; i < 64; ++i) {
    const float p = pT[i][col];
    const float4* a4 = (const float4*)&ab[i][jg * 16];
    const float4 A0 = a4[0], A1 = a4[1], A2 = a4[2], A3 = a4[3];
    accJ[0]  = fmaf(p, A0.x, accJ[0]);  accJ[1]  = fmaf(p, A0.y, accJ[1]);
    accJ[2]  = fmaf(p, A0.z, accJ[2]);  accJ[3]  = fmaf(p, A0.w, accJ[3]);
    accJ[4]  = fmaf(p, A1.x, accJ[4]);  accJ[5]  = fmaf(p, A1.y, accJ[5]);
    accJ[6]  = fmaf(p, A1.z, accJ[6]);  accJ[7]  = fmaf(p, A1.w, accJ[7]);
    accJ[8]  = fmaf(p, A2.x, accJ[8]);  accJ[9]  = fmaf(p, A2.y, accJ[9]);
    accJ[10] = fmaf(p, A2.z, accJ[10]); accJ[11] = fmaf(p, A2.w, accJ[11]);
    accJ[12] = fmaf(p, A3.x, accJ[12]); accJ[13] = fmaf(p, A3.y, accJ[13]);
    accJ[14] = fmaf(p, A3.z, accJ[14]); accJ[15] = fmaf(p, A3.w, accJ[15]);
  }
  bf16x8 u0, u1;
#pragma unroll
  for (int c = 0; c < 8; ++c) { u0[c] = (__bf16)accJ[c]; u1[c] = (__bf16)accJ[8 + c]; }
  __bf16* wp = W2 + ((size_t)b * CC + co0 + col) * CC + h * 64 + jg * 16;
  *(bf16x8*)(wp)     = u0;
  *(bf16x8*)(wp + 8) = u1;
}

// ---------------------------------------------------------------------------
// Kernel 4: per-batch GEMM  out[b,n,co] = sum_c' vb[b,n,c'] * W2[b,co,c'] + pb[co]
// m97 recipe; bijective XCD swizzle (1536 blocks, 192/XCD = one batch per XCD:
// W2 panel L2-resident, A-panel 6x reuse XCD-local).
// ---------------------------------------------------------------------------
__global__ __launch_bounds__(256) void k4_gemm(const __bf16* __restrict__ vb,
                                               const __bf16* __restrict__ W2,
                                               const float* __restrict__ pb,
                                               float* __restrict__ out) {
  const int id0 = blockIdx.x;
  const int id = (id0 & 7) * 192 + (id0 >> 3);   // bijective: 1536 % 8 == 0
  const int bz = id / 192;
  const int rem = id - bz * 192;
  const int mg = rem / 48;
  const int idx = rem - mg * 48;
  const int nt = idx >> 3;
  const int mt = mg * 8 + (idx & 7);
  const int m0 = mt * 128, co0 = nt * 128;

  __shared__ __bf16 At[128][32];
  __shared__ __bf16 Bt[128][32];

  const int tid  = threadIdx.x;
  const int w    = tid >> 6, lane = tid & 63;
  const int wm   = w >> 1,   wn   = w & 1;
  const int fr   = lane & 15;
  const int fk   = lane >> 4;

  f32x4 acc[4][4];
#pragma unroll
  for (int tm = 0; tm < 4; ++tm)
#pragma unroll
    for (int tn = 0; tn < 4; ++tn) acc[tm][tn] = (f32x4){0.f, 0.f, 0.f, 0.f};

  const int srow = lane >> 2;
  const int scol = (lane & 3) * 8;
  const __bf16* Ag = vb + (size_t)(bz * NN + m0 + w * 32 + srow) * CC + scol;
  const __bf16* Bg = W2 + ((size_t)bz * CC + co0 + w * 32 + srow) * CC + scol;
  __bf16* lA0 = &At[w * 32][0];
  __bf16* lA1 = &At[w * 32 + 16][0];
  __bf16* lB0 = &Bt[w * 32][0];
  __bf16* lB1 = &Bt[w * 32 + 16][0];

  for (int kk = 0; kk < 24; ++kk) {
    const int kb = kk * 32;
    __syncthreads();
    gload16(Ag + kb,            lA0);
    gload16(Ag + 16 * CC + kb,  lA1);
    gload16(Bg + kb,            lB0);
    gload16(Bg + 16 * CC + kb,  lB1);
    __syncthreads();
    bf16x8 afr[4], bfr[4];
#pragma unroll
    for (int tm = 0; tm < 4; ++tm)
      afr[tm] = *(const bf16x8*)&At[wm * 64 + tm * 16 + fr][fk * 8];
#pragma unroll
    for (int tn = 0; tn < 4; ++tn)
      bfr[tn] = *(const bf16x8*)&Bt[wn * 64 + tn * 16 + fr][fk * 8];
#pragma unroll
    for (int tm = 0; tm < 4; ++tm)
#pragma unroll
      for (int tn = 0; tn < 4; ++tn)
        acc[tm][tn] = __builtin_amdgcn_mfma_f32_16x16x32_bf16(afr[tm], bfr[tn],
                                                              acc[tm][tn], 0, 0, 0);
  }

#pragma unroll
  for (int tn = 0; tn < 4; ++tn) {
    const int co = co0 + wn * 64 + tn * 16 + fr;
    const float bias = pb[co];
#pragma unroll
    for (int tm = 0; tm < 4; ++tm) {
#pragma unroll
      for (int rr = 0; rr < 4; ++rr) {
        const int row = m0 + wm * 64 + tm * 16 + fk * 4 + rr;
        out[(size_t)(bz * NN + row) * CC + co] = acc[tm][tn][rr] + bias;
      }
    }
  }
}

// ---------------------------------------------------------------------------
extern "C" void kernel_launch(void* const* d_in, const int* in_sizes, int n_in,
                              void* d_out, int out_size, void* d_ws, size_t ws_size,
                              hipStream_t stream) {
  const float* x    = (const float*)d_in[0];
  const float* temp = (const float*)d_in[1];
  const float* pw   = (const float*)d_in[2];
  const float* pb   = (const float*)d_in[3];
  float* out = (float*)d_out;
  char* ws = (char*)d_ws;

  // ws layout (bytes) — every buffer fully overwritten each call, no memset:
  //   Spart @ 0        : 16*96*4096*4 = 25,165,824
  //   Qpart @ 25165824 : 16*96*64*4   = 393,216
  //   attn  @ 25559040 : 1,572,864
  //   W2    @ 27131904 : 9,437,184
  //   vb    @ 36569088 : 50,331,648   (total ~87 MB)
  float*  Spart = (float*)(ws);
  float*  Qpart = (float*)(ws + 25165824);
  float*  attn  = (float*)(ws + 25559040);
  __bf16* W2    = (__bf16*)(ws + 27131904);
  __bf16* vb    = (__bf16*)(ws + 36569088);

  hipLaunchKernelGGL(k1_logits,  dim3(16, 12, 8), dim3(256), 0, stream, x, vb, Spart, Qpart);
  hipLaunchKernelGGL(k2_softmax, dim3(12, 8),     dim3(512), 0, stream, Spart, Qpart, temp, attn);
  hipLaunchKernelGGL(k3_w2,      dim3(12, 12, 8), dim3(256), 0, stream, attn, pw, W2);
  hipLaunchKernelGGL(k4_gemm,    dim3(1536),      dim3(256), 0, stream, vb, W2, pb, out);
}

// Round 5
// 521.712 us; speedup vs baseline: 1.0225x; 1.0051x over previous
//
#include <hip/hip_runtime.h>
#include <hip/hip_bf16.h>

#define BB 8
#define NN 4096
#define HH 12
#define CC 768
#define C3 2304

typedef float  f32x4  __attribute__((ext_vector_type(4)));
typedef __bf16 bf16x8 __attribute__((ext_vector_type(8)));
typedef __bf16 bf16x4 __attribute__((ext_vector_type(4)));

__device__ __forceinline__ void gload16(const void* g, void* l) {
  __builtin_amdgcn_global_load_lds((const __attribute__((address_space(1))) void*)g,
                                   (__attribute__((address_space(3))) void*)l, 16, 0, 0);
}

__device__ __forceinline__ unsigned int pk2(float a, float b) {
  union { __bf16 h[2]; unsigned int u; } z;
  z.h[0] = (__bf16)a; z.h[1] = (__bf16)b;
  return z.u;
}

// ---------------------------------------------------------------------------
// Kernel 1: per (b,h,slice of 256 tokens):
//   Spart[s,bh,i,j] = sum_n q[n,i] * k[n,j]/||k[n]||   (bf16 MFMA, fp32 acc)
//   Qpart[s,bh,i]   = sum_n q[n,i]^2                   (fp32)
//   vb[b*N+n][h*64+c] = (bf16) x[b,n,1536+h*64+c]      (V convert, post-loop)
// R4 restructure: q loads A-fragments straight to registers (no LDS at all);
// k is packed to u32 token-pairs and written with a 16B-block XOR swizzle
// (4 ds_write_b32/thread/step, <=4-way conflict, vs 16 scalar b16 ~16-way).
// Reads: blk = fk ^ (fr>>2) matches write blk = (tp>>2) ^ ((c>>2)&3).
// ---------------------------------------------------------------------------
__global__ __launch_bounds__(256) void k1_logits(const float* __restrict__ x,
                                                 __bf16* __restrict__ vb,
                                                 float* __restrict__ Spart,
                                                 float* __restrict__ Qpart) {
  const int slice = blockIdx.x;        // 0..15 (256 tokens each)
  const int h = blockIdx.y, b = blockIdx.z;
  const int tid = threadIdx.x;
  __shared__ __bf16 kT[2][64][40];     // [buf][chan][40]: 4 swizzled 16B blocks + pad

  const int w = tid >> 6, lane = tid & 63;
  const int fr = lane & 15, fk = lane >> 4;
  const int tp = tid >> 4;             // token-pair 0..15 (tp>>2 == w)
  const int cs = tid & 15;             // 4-chan group for k staging

  const size_t rowbase = (size_t)(b * NN + slice * 256) * C3 + h * 64;
  const float* qp = x + rowbase + w * 16 + fr;      // + tok*C3
  const float* kp = x + rowbase + 768 + cs * 4;     // + tok*C3

  const int wblk = ((w ^ (cs & 3)) << 4) + (tp & 3) * 4;  // write byte-in-row
  const int rblk = (fk ^ (fr >> 2)) << 4;                 // read block byte

  float qss = 0.f;
  f32x4 acc[4];
#pragma unroll
  for (int tn = 0; tn < 4; ++tn) acc[tn] = (f32x4){0.f, 0.f, 0.f, 0.f};

  bf16x8 afr;
  // --- prologue: step 0
  {
    const int tb = fk * 8;
    const float a0 = qp[(tb + 0) * C3], a1 = qp[(tb + 1) * C3];
    const float a2 = qp[(tb + 2) * C3], a3 = qp[(tb + 3) * C3];
    const float a4 = qp[(tb + 4) * C3], a5 = qp[(tb + 5) * C3];
    const float a6 = qp[(tb + 6) * C3], a7 = qp[(tb + 7) * C3];
    const float4 kv0 = *(const float4*)(kp + (size_t)(2 * tp) * C3);
    const float4 kv1 = *(const float4*)(kp + (size_t)(2 * tp + 1) * C3);
    float s0 = kv0.x * kv0.x + kv0.y * kv0.y + kv0.z * kv0.z + kv0.w * kv0.w;
    float s1 = kv1.x * kv1.x + kv1.y * kv1.y + kv1.z * kv1.z + kv1.w * kv1.w;
    s0 += __shfl_xor(s0, 1); s1 += __shfl_xor(s1, 1);
    s0 += __shfl_xor(s0, 2); s1 += __shfl_xor(s1, 2);
    s0 += __shfl_xor(s0, 4); s1 += __shfl_xor(s1, 4);
    s0 += __shfl_xor(s0, 8); s1 += __shfl_xor(s1, 8);
    const float i0 = 1.0f / fmaxf(sqrtf(s0), 1e-12f);
    const float i1 = 1.0f / fmaxf(sqrtf(s1), 1e-12f);
    char* kbz = (char*)&kT[0][0][0];
    *(unsigned int*)(kbz + (cs * 4 + 0) * 80 + wblk) = pk2(kv0.x * i0, kv1.x * i1);
    *(unsigned int*)(kbz + (cs * 4 + 1) * 80 + wblk) = pk2(kv0.y * i0, kv1.y * i1);
    *(unsigned int*)(kbz + (cs * 4 + 2) * 80 + wblk) = pk2(kv0.z * i0, kv1.z * i1);
    *(unsigned int*)(kbz + (cs * 4 + 3) * 80 + wblk) = pk2(kv0.w * i0, kv1.w * i1);
    qss = a0 * a0 + a1 * a1 + a2 * a2 + a3 * a3 +
          a4 * a4 + a5 * a5 + a6 * a6 + a7 * a7;
    afr[0] = (__bf16)a0; afr[1] = (__bf16)a1; afr[2] = (__bf16)a2; afr[3] = (__bf16)a3;
    afr[4] = (__bf16)a4; afr[5] = (__bf16)a5; afr[6] = (__bf16)a6; afr[7] = (__bf16)a7;
  }
  __syncthreads();

  for (int step = 0; step < 8; ++step) {
    const int cur = step & 1;
    float n0, n1, n2, n3, n4, n5, n6, n7;
    float4 m0, m1;
    if (step < 7) {
      const int tb = (step + 1) * 32 + fk * 8;
      n0 = qp[(tb + 0) * C3]; n1 = qp[(tb + 1) * C3];
      n2 = qp[(tb + 2) * C3]; n3 = qp[(tb + 3) * C3];
      n4 = qp[(tb + 4) * C3]; n5 = qp[(tb + 5) * C3];
      n6 = qp[(tb + 6) * C3]; n7 = qp[(tb + 7) * C3];
      m0 = *(const float4*)(kp + (size_t)((step + 1) * 32 + 2 * tp) * C3);
      m1 = *(const float4*)(kp + (size_t)((step + 1) * 32 + 2 * tp + 1) * C3);
    }
    {
      const char* kbz = (const char*)&kT[cur][0][0];
      const bf16x8 b0 = *(const bf16x8*)(kbz + (0  + fr) * 80 + rblk);
      const bf16x8 b1 = *(const bf16x8*)(kbz + (16 + fr) * 80 + rblk);
      const bf16x8 b2 = *(const bf16x8*)(kbz + (32 + fr) * 80 + rblk);
      const bf16x8 b3 = *(const bf16x8*)(kbz + (48 + fr) * 80 + rblk);
      acc[0] = __builtin_amdgcn_mfma_f32_16x16x32_bf16(afr, b0, acc[0], 0, 0, 0);
      acc[1] = __builtin_amdgcn_mfma_f32_16x16x32_bf16(afr, b1, acc[1], 0, 0, 0);
      acc[2] = __builtin_amdgcn_mfma_f32_16x16x32_bf16(afr, b2, acc[2], 0, 0, 0);
      acc[3] = __builtin_amdgcn_mfma_f32_16x16x32_bf16(afr, b3, acc[3], 0, 0, 0);
    }
    if (step < 7) {
      float s0 = m0.x * m0.x + m0.y * m0.y + m0.z * m0.z + m0.w * m0.w;
      float s1 = m1.x * m1.x + m1.y * m1.y + m1.z * m1.z + m1.w * m1.w;
      s0 += __shfl_xor(s0, 1); s1 += __shfl_xor(s1, 1);
      s0 += __shfl_xor(s0, 2); s1 += __shfl_xor(s1, 2);
      s0 += __shfl_xor(s0, 4); s1 += __shfl_xor(s1, 4);
      s0 += __shfl_xor(s0, 8); s1 += __shfl_xor(s1, 8);
      const float i0 = 1.0f / fmaxf(sqrtf(s0), 1e-12f);
      const float i1 = 1.0f / fmaxf(sqrtf(s1), 1e-12f);
      char* kbz = (char*)&kT[cur ^ 1][0][0];
      *(unsigned int*)(kbz + (cs * 4 + 0) * 80 + wblk) = pk2(m0.x * i0, m1.x * i1);
      *(unsigned int*)(kbz + (cs * 4 + 1) * 80 + wblk) = pk2(m0.y * i0, m1.y * i1);
      *(unsigned int*)(kbz + (cs * 4 + 2) * 80 + wblk) = pk2(m0.z * i0, m1.z * i1);
      *(unsigned int*)(kbz + (cs * 4 + 3) * 80 + wblk) = pk2(m0.w * i0, m1.w * i1);
      qss += n0 * n0 + n1 * n1 + n2 * n2 + n3 * n3 +
             n4 * n4 + n5 * n5 + n6 * n6 + n7 * n7;
      afr[0] = (__bf16)n0; afr[1] = (__bf16)n1; afr[2] = (__bf16)n2; afr[3] = (__bf16)n3;
      afr[4] = (__bf16)n4; afr[5] = (__bf16)n5; afr[6] = (__bf16)n6; afr[7] = (__bf16)n7;
    }
    __syncthreads();
  }

  // S partial store: C/D layout col=lane&15, row=(lane>>4)*4+reg
  const int bh = b * HH + h;
  float* Sp = Spart + ((size_t)(slice * 96 + bh)) * 4096;
#pragma unroll
  for (int tn = 0; tn < 4; ++tn)
#pragma unroll
    for (int rr = 0; rr < 4; ++rr)
      Sp[(w * 16 + fk * 4 + rr) * 64 + tn * 16 + fr] = acc[tn][rr];

  // Qpart: lane (fr,fk) holds sum over its 64 tokens for chan w*16+fr;
  // reduce over fk (lane bits 4,5), lanes 0..15 write.
  {
    float v = qss;
    v += __shfl_xor(v, 16);
    v += __shfl_xor(v, 32);
    if (lane < 16)
      Qpart[((size_t)(slice * 96 + bh)) * 64 + w * 16 + lane] = v;
  }

  // --- V pass (no barriers, fire-and-forget): 256 tokens x 64 chans
  const int t = tid >> 3, sub = tid & 7, c0v = sub * 8;
  const float* vsrc = x + (size_t)(b * NN + slice * 256) * C3 + 1536 + h * 64 + c0v;
  __bf16* vdst = vb + (size_t)(b * NN + slice * 256) * CC + h * 64 + c0v;
#pragma unroll
  for (int r = 0; r < 8; ++r) {
    const size_t tok = (size_t)(r * 32 + t);
    const float4 v0 = *(const float4*)(vsrc + tok * C3);
    const float4 v1 = *(const float4*)(vsrc + tok * C3 + 4);
    bf16x8 vv;
    vv[0] = (__bf16)v0.x; vv[1] = (__bf16)v0.y; vv[2] = (__bf16)v0.z; vv[3] = (__bf16)v0.w;
    vv[4] = (__bf16)v1.x; vv[5] = (__bf16)v1.y; vv[6] = (__bf16)v1.z; vv[7] = (__bf16)v1.w;
    *(bf16x8*)(vdst + tok * CC) = vv;
  }
}

// ---------------------------------------------------------------------------
// Kernel 2: sum 16 slice-partials, then row softmax with q-norm + temperature
// 512 thr/block, 8 lanes per row (8 cols each), grid (12,8)
// ---------------------------------------------------------------------------
__global__ __launch_bounds__(512) void k2_softmax(const float* __restrict__ Spart,
                                                  const float* __restrict__ Qpart,
                                                  const float* __restrict__ temp,
                                                  float* __restrict__ attn) {
  const int h = blockIdx.x, b = blockIdx.y;
  const int tid = threadIdx.x;
  const int i = tid >> 3;       // row 0..63
  const int g = tid & 7;        // eighth of the row (8 cols)
  const int bh = b * HH + h;
  float qs = 0.f;
#pragma unroll
  for (int s = 0; s < 16; ++s) qs += Qpart[((size_t)(s * 96 + bh)) * 64 + i];
  float v[8];
#pragma unroll
  for (int j = 0; j < 8; ++j) v[j] = 0.f;
#pragma unroll 4
  for (int s = 0; s < 16; ++s) {
    const float* Sp = Spart + ((size_t)(s * 96 + bh)) * 4096 + i * 64 + g * 8;
    const float4 t0 = *(const float4*)(Sp);
    const float4 t1 = *(const float4*)(Sp + 4);
    v[0] += t0.x; v[1] += t0.y; v[2] += t0.z; v[3] += t0.w;
    v[4] += t1.x; v[5] += t1.y; v[6] += t1.z; v[7] += t1.w;
  }
  const float rqs = 1.0f / fmaxf(sqrtf(qs), 1e-12f);
  const float tp  = temp[h] * rqs;
  float m = -3.4e38f;
#pragma unroll
  for (int j = 0; j < 8; ++j) { v[j] *= tp; m = fmaxf(m, v[j]); }
  m = fmaxf(m, __shfl_xor(m, 1));
  m = fmaxf(m, __shfl_xor(m, 2));
  m = fmaxf(m, __shfl_xor(m, 4));
  float s = 0.f;
#pragma unroll
  for (int j = 0; j < 8; ++j) { v[j] = __expf(v[j] - m); s += v[j]; }
  s += __shfl_xor(s, 1);
  s += __shfl_xor(s, 2);
  s += __shfl_xor(s, 4);
  const float inv = 1.0f / s;
  float* Ap = attn + (size_t)bh * 4096 + i * 64 + g * 8;
  float4 o0, o1;
  o0.x = v[0] * inv; o0.y = v[1] * inv; o0.z = v[2] * inv; o0.w = v[3] * inv;
  o1.x = v[4] * inv; o1.y = v[5] * inv; o1.z = v[6] * inv; o1.w = v[7] * inv;
  *(float4*)(Ap)     = o0;
  *(float4*)(Ap + 4) = o1;
}

// ---------------------------------------------------------------------------
// Kernel 3: W2[b,co,h*64+j] = sum_i proj_w[co,h*64+i] * attn[b,h,i,j]  (bf16)
// ---------------------------------------------------------------------------
__global__ __launch_bounds__(256) void k3_w2(const float* __restrict__ attn,
                                             const float* __restrict__ pw,
                                             __bf16* __restrict__ W2) {
  const int ct = blockIdx.x, h = blockIdx.y, b = blockIdx.z;
  const int co0 = ct * 64;
  __shared__ float pT[64][65];
  __shared__ float ab[64][64];
  const int tid = threadIdx.x;
  const int r = tid >> 2, c0 = (tid & 3) * 16;
  {
    const float* pp = pw + (size_t)(co0 + r) * CC + h * 64 + c0;
    const float4 p0 = *(const float4*)(pp + 0);
    const float4 p1 = *(const float4*)(pp + 4);
    const float4 p2 = *(const float4*)(pp + 8);
    const float4 p3 = *(const float4*)(pp + 12);
    const float* ap = attn + (size_t)(b * HH + h) * 4096 + r * 64 + c0;
    const float4 a0 = *(const float4*)(ap + 0);
    const float4 a1 = *(const float4*)(ap + 4);
    const float4 a2 = *(const float4*)(ap + 8);
    const float4 a3 = *(const float4*)(ap + 12);
    pT[c0 +  0][r] = p0.x; pT[c0 +  1][r] = p0.y; pT[c0 +  2][r] = p0.z; pT[c0 +  3][r] = p0.w;
    pT[c0 +  4][r] = p1.x; pT[c0 +  5][r] = p1.y; pT[c0 +  6][r] = p1.z; pT[c0 +  7][r] = p1.w;
    pT[c0 +  8][r] = p2.x; pT[c0 +  9][r] = p2.y; pT[c0 + 10][r] = p2.z; pT[c0 + 11][r] = p2.w;
    pT[c0 + 12][r] = p3.x; pT[c0 + 13][r] = p3.y; pT[c0 + 14][r] = p3.z; pT[c0 + 15][r] = p3.w;
    *(float4*)&ab[r][c0 + 0]  = a0;
    *(float4*)&ab[r][c0 + 4]  = a1;
    *(float4*)&ab[r][c0 + 8]  = a2;
    *(float4*)&ab[r][c0 + 12] = a3;
  }
  __syncthreads();
  const int col = tid & 63, jg = tid >> 6;
  float accJ[16];
#pragma unroll
  for (int c = 0; c < 16; ++c) accJ[c] = 0.f;
#pragma unroll 4
  for (int i = 0; i < 64; ++i) {
    const float p = pT[i][col];
    const float4* a4 = (const float4*)&ab[i][jg * 16];
    const float4 A0 = a4[0], A1 = a4[1], A2 = a4[2], A3 = a4[3];
    accJ[0]  = fmaf(p, A0.x, accJ[0]);  accJ[1]  = fmaf(p, A0.y, accJ[1]);
    accJ[2]  = fmaf(p, A0.z, accJ[2]);  accJ[3]  = fmaf(p, A0.w, accJ[3]);
    accJ[4]  = fmaf(p, A1.x, accJ[4]);  accJ[5]  = fmaf(p, A1.y, accJ[5]);
    accJ[6]  = fmaf(p, A1.z, accJ[6]);  accJ[7]  = fmaf(p, A1.w, accJ[7]);
    accJ[8]  = fmaf(p, A2.x, accJ[8]);  accJ[9]  = fmaf(p, A2.y, accJ[9]);
    accJ[10] = fmaf(p, A2.z, accJ[10]); accJ[11] = fmaf(p, A2.w, accJ[11]);
    accJ[12] = fmaf(p, A3.x, accJ[12]); accJ[13] = fmaf(p, A3.y, accJ[13]);
    accJ[14] = fmaf(p, A3.z, accJ[14]); accJ[15] = fmaf(p, A3.w, accJ[15]);
  }
  bf16x8 u0, u1;
#pragma unroll
  for (int c = 0; c < 8; ++c) { u0[c] = (__bf16)accJ[c]; u1[c] = (__bf16)accJ[8 + c]; }
  __bf16* wp = W2 + ((size_t)b * CC + co0 + col) * CC + h * 64 + jg * 16;
  *(bf16x8*)(wp)     = u0;
  *(bf16x8*)(wp + 8) = u1;
}

// ---------------------------------------------------------------------------
// Kernel 4: per-batch GEMM  out[b,n,co] = sum_c' vb[b,n,c'] * W2[b,co,c'] + pb[co]
// m97 recipe (R1 form, no XCD swizzle — measured neutral/negative).
// ---------------------------------------------------------------------------
__global__ __launch_bounds__(256) void k4_gemm(const __bf16* __restrict__ vb,
                                               const __bf16* __restrict__ W2,
                                               const float* __restrict__ pb,
                                               float* __restrict__ out) {
  int id = blockIdx.x;
  const int bz = id / 192;
  const int rem = id - bz * 192;
  const int mg = rem / 48;
  const int idx = rem - mg * 48;
  const int nt = idx >> 3;
  const int mt = mg * 8 + (idx & 7);
  const int m0 = mt * 128, co0 = nt * 128;

  __shared__ __bf16 At[128][32];
  __shared__ __bf16 Bt[128][32];

  const int tid  = threadIdx.x;
  const int w    = tid >> 6, lane = tid & 63;
  const int wm   = w >> 1,   wn   = w & 1;
  const int fr   = lane & 15;
  const int fk   = lane >> 4;

  f32x4 acc[4][4];
#pragma unroll
  for (int tm = 0; tm < 4; ++tm)
#pragma unroll
    for (int tn = 0; tn < 4; ++tn) acc[tm][tn] = (f32x4){0.f, 0.f, 0.f, 0.f};

  const int srow = lane >> 2;
  const int scol = (lane & 3) * 8;
  const __bf16* Ag = vb + (size_t)(bz * NN + m0 + w * 32 + srow) * CC + scol;
  const __bf16* Bg = W2 + ((size_t)bz * CC + co0 + w * 32 + srow) * CC + scol;
  __bf16* lA0 = &At[w * 32][0];
  __bf16* lA1 = &At[w * 32 + 16][0];
  __bf16* lB0 = &Bt[w * 32][0];
  __bf16* lB1 = &Bt[w * 32 + 16][0];

  for (int kk = 0; kk < 24; ++kk) {
    const int kb = kk * 32;
    __syncthreads();
    gload16(Ag + kb,            lA0);
    gload16(Ag + 16 * CC + kb,  lA1);
    gload16(Bg + kb,            lB0);
    gload16(Bg + 16 * CC + kb,  lB1);
    __syncthreads();
    bf16x8 afr[4], bfr[4];
#pragma unroll
    for (int tm = 0; tm < 4; ++tm)
      afr[tm] = *(const bf16x8*)&At[wm * 64 + tm * 16 + fr][fk * 8];
#pragma unroll
    for (int tn = 0; tn < 4; ++tn)
      bfr[tn] = *(const bf16x8*)&Bt[wn * 64 + tn * 16 + fr][fk * 8];
#pragma unroll
    for (int tm = 0; tm < 4; ++tm)
#pragma unroll
      for (int tn = 0; tn < 4; ++tn)
        acc[tm][tn] = __builtin_amdgcn_mfma_f32_16x16x32_bf16(afr[tm], bfr[tn],
                                                              acc[tm][tn], 0, 0, 0);
  }

#pragma unroll
  for (int tn = 0; tn < 4; ++tn) {
    const int co = co0 + wn * 64 + tn * 16 + fr;
    const float bias = pb[co];
#pragma unroll
    for (int tm = 0; tm < 4; ++tm) {
#pragma unroll
      for (int rr = 0; rr < 4; ++rr) {
        const int row = m0 + wm * 64 + tm * 16 + fk * 4 + rr;
        out[(size_t)(bz * NN + row) * CC + co] = acc[tm][tn][rr] + bias;
      }
    }
  }
}

// ---------------------------------------------------------------------------
extern "C" void kernel_launch(void* const* d_in, const int* in_sizes, int n_in,
                              void* d_out, int out_size, void* d_ws, size_t ws_size,
                              hipStream_t stream) {
  const float* x    = (const float*)d_in[0];
  const float* temp = (const float*)d_in[1];
  const float* pw   = (const float*)d_in[2];
  const float* pb   = (const float*)d_in[3];
  float* out = (float*)d_out;
  char* ws = (char*)d_ws;

  // ws layout (bytes) — every buffer fully overwritten each call, no memset:
  //   Spart @ 0        : 16*96*4096*4 = 25,165,824
  //   Qpart @ 25165824 : 16*96*64*4   = 393,216
  //   attn  @ 25559040 : 1,572,864
  //   W2    @ 27131904 : 9,437,184
  //   vb    @ 36569088 : 50,331,648   (total ~87 MB)
  float*  Spart = (float*)(ws);
  float*  Qpart = (float*)(ws + 25165824);
  float*  attn  = (float*)(ws + 25559040);
  __bf16* W2    = (__bf16*)(ws + 27131904);
  __bf16* vb    = (__bf16*)(ws + 36569088);

  hipLaunchKernelGGL(k1_logits,  dim3(16, 12, 8), dim3(256), 0, stream, x, vb, Spart, Qpart);
  hipLaunchKernelGGL(k2_softmax, dim3(12, 8),     dim3(512), 0, stream, Spart, Qpart, temp, attn);
  hipLaunchKernelGGL(k3_w2,      dim3(12, 12, 8), dim3(256), 0, stream, attn, pw, W2);
  hipLaunchKernelGGL(k4_gemm,    dim3(1536),      dim3(256), 0, stream, vb, W2, pb, out);
}